// Round 5
// baseline (915.784 us; speedup 1.0000x reference)
//
#include <hip/hip_runtime.h>
#include <stdint.h>

#define B_ROWS 8192
#define K_DIM 2048
#define N_DIM 2048
#define NPOP 8

typedef float f32x4 __attribute__((ext_vector_type(4)));
typedef __bf16 bf16x8 __attribute__((ext_vector_type(8)));

// gid 0..27 = unordered pairs (a<b), lexicographic; 28..35 = slot-0 expert
// (fallback); 36..43 = slot-1 expert (fallback). Diagonal entries let
// bias = bs_scale*(b[e1]+b[e2]) serve both paths.
__constant__ unsigned char c_pa[44] = {
  0,0,0,0,0,0,0, 1,1,1,1,1,1, 2,2,2,2,2, 3,3,3,3, 4,4,4, 5,5, 6,
  0,1,2,3,4,5,6,7, 0,1,2,3,4,5,6,7};
__constant__ unsigned char c_pb[44] = {
  1,2,3,4,5,6,7, 2,3,4,5,6,7, 3,4,5,6,7, 4,5,6,7, 5,6,7, 6,7, 7,
  0,1,2,3,4,5,6,7, 0,1,2,3,4,5,6,7};

__device__ __forceinline__ unsigned short f2bf(float f) {
  unsigned int u = __float_as_uint(f);
  u += 0x7fffu + ((u >> 16) & 1u);   // RNE
  return (unsigned short)(u >> 16);
}

// pack two f32 -> two bf16 (round-half-up; error <= ulp/2, fine vs 4.9e-2 thr)
__device__ __forceinline__ unsigned int pack2bf(float lo, float hi) {
  unsigned int ul = __float_as_uint(lo) + 0x8000u;
  unsigned int uh = __float_as_uint(hi) + 0x8000u;
  return (ul >> 16) | (uh & 0xffff0000u);
}

// async global->LDS, 16B/lane; LDS dest = wave-uniform base + lane*16
__device__ __forceinline__ void glds16(const unsigned short* g, unsigned short* l) {
  __builtin_amdgcn_global_load_lds(
      (__attribute__((address_space(1))) unsigned int*)g,
      (__attribute__((address_space(3))) unsigned int*)l, 16, 0, 0);
}

// ---- fallback: W fp32 -> bf16 ----
__global__ void prep_w_kernel(const float* __restrict__ W, unsigned short* __restrict__ Wb) {
  const int n4 = NPOP * N_DIM * K_DIM / 4;
  int stride = gridDim.x * blockDim.x;
  for (int i = blockIdx.x * blockDim.x + threadIdx.x; i < n4; i += stride) {
    float4 v = reinterpret_cast<const float4*>(W)[i];
    ushort4 s;
    s.x = f2bf(v.x); s.y = f2bf(v.y); s.z = f2bf(v.z); s.w = f2bf(v.w);
    reinterpret_cast<ushort4*>(Wb)[i] = s;
  }
}

// ---- fused: read W once, emit all 28 pair averages (0.5 combine folded in) ----
// thread f handles float4 plane offset f for all experts: 134 MB read + 235 MB write
__global__ __launch_bounds__(256) void prep_wpair_kernel(const float* __restrict__ W,
                                                         unsigned short* __restrict__ Wp) {
  const int f = blockIdx.x * 256 + threadIdx.x;   // 0 .. 2048*2048/4 - 1
  const int plane4 = N_DIM * K_DIM / 4;
  float4 wv[NPOP];
#pragma unroll
  for (int p = 0; p < NPOP; ++p)
    wv[p] = reinterpret_cast<const float4*>(W)[(size_t)p * plane4 + f];
  uint2* dst = reinterpret_cast<uint2*>(Wp);
  int pid = 0;
#pragma unroll
  for (int a = 0; a < NPOP - 1; ++a)
#pragma unroll
    for (int bq = a + 1; bq < NPOP; ++bq) {
      float sx = 0.5f * (wv[a].x + wv[bq].x);
      float sy = 0.5f * (wv[a].y + wv[bq].y);
      float sz = 0.5f * (wv[a].z + wv[bq].z);
      float sw = 0.5f * (wv[a].w + wv[bq].w);
      uint2 q;
      q.x = pack2bf(sx, sy);
      q.y = pack2bf(sz, sw);
      dst[(size_t)pid * plane4 + f] = q;
      ++pid;
    }
}

// ---- selector (fp32, Ws in LDS, fragments hoisted to regs) + x->bf16 ----
__global__ __launch_bounds__(256) void sel_conv_x_kernel(
    const float* __restrict__ x, const float* __restrict__ Ws,
    const float* __restrict__ bs, unsigned short* __restrict__ xb,
    int* __restrict__ sel) {
  __shared__ float ws_l[NPOP * K_DIM];   // 64 KB
  const int t = threadIdx.x;
  const float4* Ws4 = reinterpret_cast<const float4*>(Ws);
  float4* wsl4 = reinterpret_cast<float4*>(ws_l);
#pragma unroll
  for (int i = 0; i < NPOP * K_DIM / 4 / 256; ++i)
    wsl4[i * 256 + t] = Ws4[i * 256 + t];
  __syncthreads();

  const int w = t >> 6, l = t & 63;
  const float4* x4 = reinterpret_cast<const float4*>(x);

  float acc[4][NPOP];
#pragma unroll
  for (int rr = 0; rr < 4; ++rr)
#pragma unroll
    for (int p = 0; p < NPOP; ++p) acc[rr][p] = 0.f;

#pragma unroll
  for (int j = 0; j < 8; ++j) {
    int idx = j * 256 + l * 4;
    float4 wv[NPOP];
#pragma unroll
    for (int p = 0; p < NPOP; ++p) wv[p] = wsl4[(p * K_DIM + idx) >> 2];
#pragma unroll
    for (int rr = 0; rr < 4; ++rr) {
      int r = blockIdx.x * 16 + rr * 4 + w;
      float4 v = x4[((size_t)r * K_DIM + idx) >> 2];
      ushort4 s;
      unsigned int q0 = pack2bf(v.x, v.y), q1 = pack2bf(v.z, v.w);
      s.x = (unsigned short)q0; s.y = (unsigned short)(q0 >> 16);
      s.z = (unsigned short)q1; s.w = (unsigned short)(q1 >> 16);
      *reinterpret_cast<ushort4*>(xb + (size_t)r * K_DIM + idx) = s;
#pragma unroll
      for (int p = 0; p < NPOP; ++p)
        acc[rr][p] += v.x * wv[p].x + v.y * wv[p].y + v.z * wv[p].z + v.w * wv[p].w;
    }
  }

#pragma unroll
  for (int rr = 0; rr < 4; ++rr) {
#pragma unroll
    for (int off = 32; off > 0; off >>= 1)
#pragma unroll
      for (int p = 0; p < NPOP; ++p) acc[rr][p] += __shfl_xor(acc[rr][p], off, 64);
    if (l == 0) {
      int r = blockIdx.x * 16 + rr * 4 + w;
      float lg[NPOP];
#pragma unroll
      for (int p = 0; p < NPOP; ++p) lg[p] = acc[rr][p] + bs[p];
      int p1 = 0;
#pragma unroll
      for (int p = 1; p < NPOP; ++p) if (lg[p] > lg[p1]) p1 = p;  // strict >: low idx ties
      int p2 = -1;
#pragma unroll
      for (int p = 0; p < NPOP; ++p) {
        if (p == p1) continue;
        if (p2 < 0 || lg[p] > lg[p2]) p2 = p;
      }
      sel[r] = p1 * 8 + p2;
    }
  }
}

// ---- build 44 row lists; two-scan, NO private array (avoids scratch spills) ----
__device__ __forceinline__ bool list_match(int gid, int s) {
  int p1 = s >> 3, p2 = s & 7;
  if (gid < 28) {
    int a = p1 < p2 ? p1 : p2, bb = p1 < p2 ? p2 : p1;
    return (a == c_pa[gid]) && (bb == c_pb[gid]);
  } else if (gid < 36) {
    return p1 == gid - 28;
  }
  return p2 == gid - 36;
}

__global__ __launch_bounds__(256) void build_lists_kernel(const int* __restrict__ sel,
                                                          int* __restrict__ lists,
                                                          int* __restrict__ cnt) {
  const int gid = blockIdx.x;       // 0..43
  const int t   = threadIdx.x;
  __shared__ int psum[256];
  int c = 0;
#pragma unroll
  for (int i = 0; i < 32; ++i)
    c += list_match(gid, sel[i * 256 + t]) ? 1 : 0;
  psum[t] = c;
  __syncthreads();
  for (int off = 1; off < 256; off <<= 1) {
    int v = (t >= off) ? psum[t - off] : 0;
    __syncthreads();
    psum[t] += v;
    __syncthreads();
  }
  int pos = psum[t] - c;
#pragma unroll
  for (int i = 0; i < 32; ++i) {
    int r = i * 256 + t;
    if (list_match(gid, sel[r])) {
      if (pos < 2048) lists[gid * 2048 + pos] = r;
      ++pos;
    }
  }
  if (t == 255) cnt[gid] = psum[255] < 2048 ? psum[255] : 2048;
}

// ---- grouped GEMM, 128x128 tile, 4 waves, BK=32, XOR-swizzled LDS ----
__global__ __launch_bounds__(256) void gemm_kernel(
    const unsigned short* __restrict__ xb,
    const unsigned short* __restrict__ Wstack,
    const float* __restrict__ bvec,
    const int* __restrict__ lists,
    const int* __restrict__ cnt,
    float* __restrict__ out,
    int gid_base, float acc_scale, float bias_scale, int rmw) {
  const int z   = blockIdx.z;
  const int gid = gid_base + z;
  const int cg  = cnt[gid];
  const int m0  = blockIdx.x * 128;
  if (m0 >= cg) return;
  const int n0 = blockIdx.y * 128;
  const int e1 = c_pa[gid], e2 = c_pb[gid];

  __shared__ __align__(16) unsigned short As[128 * 32];
  __shared__ __align__(16) unsigned short Bs[128 * 32];
  __shared__ int   sh_rows[128];
  __shared__ float sh_bias[128];

  const int t = threadIdx.x;
  const int w = t >> 6;
  const int l = t & 63;

  const int* list = lists + gid * 2048;
  if (t < 128) {
    int idx = m0 + t;
    sh_rows[t] = (idx < cg) ? list[idx] : -1;
    sh_bias[t] = bias_scale * (bvec[e1 * N_DIM + n0 + t] + bvec[e2 * N_DIM + n0 + t]);
  }
  __syncthreads();

  const int rg = l >> 2;
  const int ck = l & 3;
  const int tra0 = 32 * w + rg;
  const int tra1 = tra0 + 16;
  int ar0 = sh_rows[tra0]; if (ar0 < 0) ar0 = 0;
  int ar1 = sh_rows[tra1]; if (ar1 < 0) ar1 = 0;
  const unsigned short* ap0 = xb + (size_t)ar0 * K_DIM + ((ck ^ ((tra0 >> 1) & 3)) * 8);
  const unsigned short* ap1 = xb + (size_t)ar1 * K_DIM + ((ck ^ ((tra1 >> 1) & 3)) * 8);
  const unsigned short* wb0 = Wstack + ((size_t)(gid - gid_base >= 0 ? z : z)) * 0;  // (no-op, keep z)
  const unsigned short* wbase = Wstack + (size_t)z * N_DIM * K_DIM;
  (void)wb0;
  const unsigned short* bp0 = wbase + (size_t)(n0 + tra0) * K_DIM + ((ck ^ ((tra0 >> 1) & 3)) * 8);
  const unsigned short* bp1 = wbase + (size_t)(n0 + tra1) * K_DIM + ((ck ^ ((tra1 >> 1) & 3)) * 8);

  unsigned short* As_d0 = As + (2 * w) * 512;
  unsigned short* As_d1 = As + (2 * w + 1) * 512;
  unsigned short* Bs_d0 = Bs + (2 * w) * 512;
  unsigned short* Bs_d1 = Bs + (2 * w + 1) * 512;

  const int wm = w >> 1, wn = w & 1;
  const int lane16 = l & 15;
  const int quad   = l >> 4;

  const unsigned short* afp[4];
  const unsigned short* bfp[4];
#pragma unroll
  for (int mi = 0; mi < 4; ++mi) {
    int r = wm * 64 + mi * 16 + lane16;
    afp[mi] = &As[r * 32 + ((quad ^ ((r >> 1) & 3)) * 8)];
  }
#pragma unroll
  for (int ni = 0; ni < 4; ++ni) {
    int r = wn * 64 + ni * 16 + lane16;
    bfp[ni] = &Bs[r * 32 + ((quad ^ ((r >> 1) & 3)) * 8)];
  }

  f32x4 acc[4][4];
#pragma unroll
  for (int i = 0; i < 4; ++i)
#pragma unroll
    for (int j = 0; j < 4; ++j) { f32x4 zz = {0.f, 0.f, 0.f, 0.f}; acc[i][j] = zz; }

  for (int k0 = 0; k0 < K_DIM; k0 += 32) {
    glds16(ap0 + k0, As_d0);
    glds16(ap1 + k0, As_d1);
    glds16(bp0 + k0, Bs_d0);
    glds16(bp1 + k0, Bs_d1);
    __syncthreads();

    bf16x8 af[4], bf[4];
#pragma unroll
    for (int mi = 0; mi < 4; ++mi) af[mi] = *reinterpret_cast<const bf16x8*>(afp[mi]);
#pragma unroll
    for (int ni = 0; ni < 4; ++ni) bf[ni] = *reinterpret_cast<const bf16x8*>(bfp[ni]);
#pragma unroll
    for (int mi = 0; mi < 4; ++mi)
#pragma unroll
      for (int ni = 0; ni < 4; ++ni)
        acc[mi][ni] = __builtin_amdgcn_mfma_f32_16x16x32_bf16(af[mi], bf[ni], acc[mi][ni], 0, 0, 0);
    __syncthreads();
  }

#pragma unroll
  for (int mi = 0; mi < 4; ++mi) {
#pragma unroll
    for (int i = 0; i < 4; ++i) {
      int trow = wm * 64 + mi * 16 + quad * 4 + i;
      int r = sh_rows[trow];
      if (r < 0) continue;
      float* orow = out + (size_t)r * N_DIM + n0;
#pragma unroll
      for (int ni = 0; ni < 4; ++ni) {
        int colL = wn * 64 + ni * 16 + lane16;
        float v = acc_scale * acc[mi][ni][i] + sh_bias[colL];
        if (rmw) orow[colL] += v;
        else     orow[colL] = v;
      }
    }
  }
}

extern "C" void kernel_launch(void* const* d_in, const int* in_sizes, int n_in,
                              void* d_out, int out_size, void* d_ws, size_t ws_size,
                              hipStream_t stream) {
  const float* x  = (const float*)d_in[0];
  const float* W  = (const float*)d_in[1];
  const float* b  = (const float*)d_in[2];
  const float* Ws = (const float*)d_in[3];
  const float* bs = (const float*)d_in[4];
  float* out = (float*)d_out;

  const size_t WPAIR_BYTES = (size_t)28 * N_DIM * K_DIM * 2;   // 235 MB
  const size_t WB_BYTES    = (size_t)NPOP * N_DIM * K_DIM * 2; //  67 MB
  const size_t XB_BYTES    = (size_t)B_ROWS * K_DIM * 2;       //  33.5 MB
  const size_t LISTS_BYTES = (size_t)44 * 2048 * 4;
  const size_t CNT_BYTES   = 256;
  const size_t SEL_BYTES   = (size_t)B_ROWS * 4;

  bool fused = ws_size >= WPAIR_BYTES + XB_BYTES + LISTS_BYTES + CNT_BYTES + SEL_BYTES;
  size_t wbytes = fused ? WPAIR_BYTES : WB_BYTES;

  char* ws = (char*)d_ws;
  unsigned short* Wks = (unsigned short*)ws;
  unsigned short* xb  = (unsigned short*)(ws + wbytes);
  int* lists = (int*)(ws + wbytes + XB_BYTES);
  int* cnt   = (int*)(ws + wbytes + XB_BYTES + LISTS_BYTES);
  int* sel   = (int*)(ws + wbytes + XB_BYTES + LISTS_BYTES + CNT_BYTES);

  if (fused) {
    // prep first; sel/build's ~100 MB of traffic evicts the LRU (low-gid) half
    // of Wpair from L3, so run the high-gid GEMM slice first.
    prep_wpair_kernel<<<4096, 256, 0, stream>>>(W, Wks);
    sel_conv_x_kernel<<<512, 256, 0, stream>>>(x, Ws, bs, xb, sel);
    build_lists_kernel<<<44, 256, 0, stream>>>(sel, lists, cnt);
    gemm_kernel<<<dim3(16, 16, 14), 256, 0, stream>>>(xb, Wks + (size_t)14 * N_DIM * K_DIM,
                                                      b, lists, cnt, out, 14, 1.0f, 0.5f, 0);
    gemm_kernel<<<dim3(16, 16, 14), 256, 0, stream>>>(xb, Wks, b, lists, cnt, out,
                                                      0, 1.0f, 0.5f, 0);
  } else {
    prep_w_kernel<<<4096, 256, 0, stream>>>(W, Wks);
    sel_conv_x_kernel<<<512, 256, 0, stream>>>(x, Ws, bs, xb, sel);
    build_lists_kernel<<<44, 256, 0, stream>>>(sel, lists, cnt);
    gemm_kernel<<<dim3(16, 16, 8), 256, 0, stream>>>(xb, Wks, b, lists, cnt, out,
                                                     28, 0.5f, 0.25f, 0);
    gemm_kernel<<<dim3(16, 16, 8), 256, 0, stream>>>(xb, Wks, b, lists, cnt, out,
                                                     36, 0.5f, 0.25f, 1);
  }
}